// Round 12
// baseline (314.474 us; speedup 1.0000x reference)
//
#include <hip/hip_runtime.h>
#include <hip/hip_bf16.h>

typedef _Float16 f16x8 __attribute__((ext_vector_type(8)));
typedef _Float16 f16x4 __attribute__((ext_vector_type(4)));
typedef float f32x4 __attribute__((ext_vector_type(4)));

#define B_SZ 64
#define T_SZ 2048
#define D_SZ 300
#define M_SZ (B_SZ * T_SZ)      // 131072
#define KP 320                   // padded K for W
#define NP 640                   // padded combined N (z: 0..299, o: 320..619)
#define NCHUNK 32
#define CLEN 64                  // T / NCHUNK

__device__ __forceinline__ void gld_lds16(const void* g, void* l) {
    __builtin_amdgcn_global_load_lds(
        (const __attribute__((address_space(1))) unsigned int*)g,
        (__attribute__((address_space(3))) unsigned int*)l,
        16, 0, 0);
}

__device__ __forceinline__ float fast_tanh(float x) {
    float e = __expf(2.0f * x);
    return 1.0f - 2.0f * __builtin_amdgcn_rcpf(e + 1.0f);
}

__device__ __forceinline__ f16x8 cvt8(f32x4 v0, f32x4 v1) {
    f16x8 r;
    r[0] = (_Float16)v0[0]; r[1] = (_Float16)v0[1];
    r[2] = (_Float16)v0[2]; r[3] = (_Float16)v0[3];
    r[4] = (_Float16)v1[0]; r[5] = (_Float16)v1[1];
    r[6] = (_Float16)v1[2]; r[7] = (_Float16)v1[3];
    return r;
}

// ---- pack Wz/Wo fp32 [300,300] -> combined fp16 [640,320], zero-padded ----
// k-pad zeros (300..319) also cancel the garbage/zeroed A tail values.
__global__ void pack_w(const float* __restrict__ Wz, const float* __restrict__ Wo,
                       _Float16* __restrict__ W) {
    unsigned int i = blockIdx.x * 256u + threadIdx.x;
    if (i >= NP * KP) return;
    unsigned int n = i / KP;
    unsigned int k = i - n * KP;
    float v = 0.0f;
    if (k < D_SZ) {
        if (n < D_SZ) v = Wz[n * D_SZ + k];
        else if (n >= 320 && n < 320 + D_SZ) v = Wo[(n - 320) * D_SZ + k];
    }
    W[i] = (_Float16)v;
}

__global__ void pack_bias(const float* __restrict__ bz, const float* __restrict__ bo,
                          float* __restrict__ bias, float* __restrict__ zpad) {
    int n = threadIdx.x;
    float v = 0.0f;
    if (n < D_SZ) v = bz[n];
    else if (n >= 320 && n < 320 + D_SZ) v = bo[n - 320];
    bias[n] = v;
    if (n < 16) zpad[n] = 0.0f;
}

// ---- GEMM: C16[m][n] = tanh( sum_k X[m][k]*W[n][k] + bias[n] ), fp16 out ----
// R9 recipe with A read DIRECTLY from fp32 X (no pack_x). A-LDS uses the
// PROVEN-conflict-free 64B-row geometry: [2 k-half][128 m][16 fp32]. LDS row
// = h*128+m, so octets mix row parity (l15&1) and unit XOR ((l15>>1)&3) ->
// all 32 banks per octet (same byte-geometry as the 0-conflict f16 B-path).
// Fragments: 2x ds_read_b128 fp32 + cvt8 in reg (VALU overlaps MFMA pipe).
__global__ __launch_bounds__(256) void gemm_zo(const float* __restrict__ X,
                                               const _Float16* __restrict__ W,
                                               const float* __restrict__ bias,
                                               const float* __restrict__ zpad,
                                               _Float16* __restrict__ C) {
    __shared__ float    Asf[2][2 * 128 * 16];  // 16 KB each: [h][m][16 fp32]
    __shared__ _Float16 Bs[2][128 * 32];       // 8 KB each

    const int tid = threadIdx.x;
    const int lane = tid & 63;
    const int wid = tid >> 6;              // 0..3
    const int wm = wid >> 1, wn = wid & 1;

    // XCD-aware swizzle (5120 blocks, 5120 % 8 == 0 -> bijective); 5 bn-tiles
    // of one bm consecutive on one XCD -> X re-read is L2-served.
    int g = blockIdx.x;
    int s = (g & 7) * (5120 / 8) + (g >> 3);
    int bm = s / 5;          // 1024 M-tiles
    int bn = s - bm * 5;     // 5 N-tiles

    const int l15 = lane & 15;
    const int kq = lane >> 4;

    f32x4 acc[4][4] = {};

    // A staging: 16 instrs/step = [h 0..1][m-chunk c 0..7], 16 rows x 64B each.
    // lane -> r_in = lane>>2, u = lane&3; source unit pre-swizzled by
    // (r_in>>1)&3 (== (m>>1)&3 since c*16 contributes 0 mod 4 after >>1).
    const int ar_in = lane >> 2;
    const int a_u = lane & 3;
    const int a_us = a_u ^ ((ar_in >> 1) & 3);
    // B staging: 8 chunks of 16 rows; wave stages 2 (proven pattern).
    const int brow_in = lane >> 2;
    const int bsrc_u = (lane & 3) ^ ((brow_in >> 1) & 3);

    auto stage = [&](int buf, int kt) {
        const bool tail = (kt == 9);
#pragma unroll
        for (int j = 0; j < 4; ++j) {
            int idx = wid + j * 4;         // 0..15
            int h = idx >> 3;              // k-half
            int c = idx & 7;               // m-chunk
            int m = c * 16 + ar_in;
            int koff = kt * 32 + h * 16 + a_us * 4;
            const float* src = (tail && (h * 16 + a_us * 4) >= 12)
                ? zpad
                : X + (size_t)(bm * 128 + m) * D_SZ + koff;
            gld_lds16(src, &Asf[buf][h * 2048 + c * 256]);
        }
#pragma unroll
        for (int j = 0; j < 2; ++j) {
            int c = wid + j * 4;
            int row = c * 16 + brow_in;
            gld_lds16(W + (size_t)(bn * 128 + row) * KP + kt * 32 + bsrc_u * 8,
                      &Bs[buf][c * 512]);
        }
    };

    stage(0, 0);
    __syncthreads();

    const int ah = kq >> 1;                // k-half for this lane's fragment
    const int alo = (kq & 1) * 2;          // local lo unit before swizzle
    const int axr = (l15 >> 1) & 3;        // unit XOR key

    int buf = 0;
#pragma unroll 1
    for (int kt = 0; kt < 10; ++kt) {
        if (kt < 9) stage(buf ^ 1, kt + 1);

        f16x8 bf[4], af[4];
#pragma unroll
        for (int ns = 0; ns < 4; ++ns) {
            int row = wn * 64 + ns * 16 + l15;
            int u = kq ^ ((row >> 1) & 3);
            bf[ns] = *(const f16x8*)&Bs[buf][row * 32 + u * 8];
        }
#pragma unroll
        for (int ms = 0; ms < 4; ++ms) {
            int m = wm * 64 + ms * 16 + l15;
            f32x4 lo = *(const f32x4*)&Asf[buf][ah * 2048 + m * 16 + (alo ^ axr) * 4];
            f32x4 hi = *(const f32x4*)&Asf[buf][ah * 2048 + m * 16 + ((alo + 1) ^ axr) * 4];
            af[ms] = cvt8(lo, hi);
        }

        __builtin_amdgcn_s_setprio(1);
#pragma unroll
        for (int ms = 0; ms < 4; ++ms)
#pragma unroll
            for (int ns = 0; ns < 4; ++ns)
                acc[ms][ns] = __builtin_amdgcn_mfma_f32_16x16x32_f16(bf[ns], af[ms], acc[ms][ns], 0, 0, 0);
        __builtin_amdgcn_s_setprio(0);

        __syncthreads();
        buf ^= 1;
    }

    // ---- epilogue: LDS-shuffled, fully-coalesced full-line stores (R9) ----
    // swapped layout: value (ms,ns,r) sits at m = mrow0+ms*16+l15,
    //                                     n = ncol0+ns*16+kq*4+r
    __syncthreads();
    _Float16* et = (_Float16*)&Asf[0][0] + wid * 1024;  // [16][64] f16, wave-private

    const int mrow0 = bm * 128 + wm * 64;
    const int ncol0 = bn * 128 + wn * 64;
    const int row8 = lane >> 3;            // 0..7
    const int u8 = lane & 7;               // logical 16B unit within 128B row

    f32x4 b4[4];
#pragma unroll
    for (int ns = 0; ns < 4; ++ns)
        b4[ns] = *(const f32x4*)&bias[ncol0 + ns * 16 + kq * 4];

#pragma unroll
    for (int ms = 0; ms < 4; ++ms) {
#pragma unroll
        for (int ns = 0; ns < 4; ++ns) {
            f16x4 v;
#pragma unroll
            for (int r = 0; r < 4; ++r)
                v[r] = (_Float16)fast_tanh(acc[ms][ns][r] + b4[ns][r]);
            int up = ((ns << 1) | (kq >> 1)) ^ (l15 & 7);
            *(f16x4*)&et[l15 * 64 + up * 8 + (kq & 1) * 4] = v;
        }
#pragma unroll
        for (int j = 0; j < 2; ++j) {
            int rr = row8 + j * 8;
            f16x8 o = *(const f16x8*)&et[rr * 64 + (u8 ^ (rr & 7)) * 8];
            *(f16x8*)&C[(size_t)(mrow0 + ms * 16 + rr) * NP + ncol0 + u8 * 8] = o;
        }
    }
}

// ---- scan phase 1: per (b, chunk, d) compute affine (A = prod g, Bc) ----
__global__ void scan_p1(const float* __restrict__ gate, const _Float16* __restrict__ C,
                        float* __restrict__ Aout, float* __restrict__ Bout) {
    int b = blockIdx.x >> 5;
    int nc = blockIdx.x & 31;
    int d = threadIdx.x;
    if (d >= D_SZ) return;
    size_t base = (size_t)b * T_SZ + (size_t)nc * CLEN;
    const float* gp = gate + base * D_SZ + d;
    const _Float16* zp = C + base * NP + d;
    float A = 1.0f, Bc = 0.0f;
    for (int t = 0; t < CLEN; ++t) {
        float gv = gp[(size_t)t * D_SZ];
        float zv = (float)zp[(size_t)t * NP];
        A *= gv;
        Bc = gv * Bc + (1.0f - gv) * zv;
    }
    int o = (b * NCHUNK + nc) * D_SZ + d;
    Aout[o] = A;
    Bout[o] = Bc;
}

// ---- scan phase 2: sequential scan over the 32 chunk summaries ----
__global__ void scan_p2(const float* __restrict__ A, const float* __restrict__ Bc,
                        float* __restrict__ Cin) {
    int idx = blockIdx.x * 256 + threadIdx.x;
    if (idx >= B_SZ * D_SZ) return;
    int b = idx / D_SZ;
    int d = idx - b * D_SZ;
    float c = 0.0f;
    for (int nc = 0; nc < NCHUNK; ++nc) {
        int o = (b * NCHUNK + nc) * D_SZ + d;
        Cin[o] = c;
        c = A[o] * c + Bc[o];
    }
}

// ---- scan phase 3: replay chunk with correct c_in, write h = o * c ----
__global__ void scan_p3(const float* __restrict__ gate, const _Float16* __restrict__ C,
                        const float* __restrict__ Cin, float* __restrict__ out) {
    int b = blockIdx.x >> 5;
    int nc = blockIdx.x & 31;
    int d = threadIdx.x;
    if (d >= D_SZ) return;
    size_t base = (size_t)b * T_SZ + (size_t)nc * CLEN;
    const float* gp = gate + base * D_SZ + d;
    const _Float16* zp = C + base * NP + d;
    const _Float16* op = zp + 320;
    float* hp = out + base * D_SZ + d;
    float c = Cin[(b * NCHUNK + nc) * D_SZ + d];
    for (int t = 0; t < CLEN; ++t) {
        float gv = gp[(size_t)t * D_SZ];
        float zv = (float)zp[(size_t)t * NP];
        float ov = (float)op[(size_t)t * NP];
        c = gv * c + (1.0f - gv) * zv;
        hp[(size_t)t * D_SZ] = ov * c;
    }
}

extern "C" void kernel_launch(void* const* d_in, const int* in_sizes, int n_in,
                              void* d_out, int out_size, void* d_ws, size_t ws_size,
                              hipStream_t stream) {
    const float* gate = (const float*)d_in[0];
    const float* xin  = (const float*)d_in[1];
    const float* Wz   = (const float*)d_in[2];
    const float* bz   = (const float*)d_in[3];
    const float* Wo   = (const float*)d_in[4];
    const float* bo   = (const float*)d_in[5];
    float* out = (float*)d_out;

    char* ws = (char*)d_ws;
    _Float16* C16  = (_Float16*)(ws);                       // M*NP*2      = 167,772,160
    _Float16* Wc   = (_Float16*)(ws + 167772160ull);        // NP*KP*2     = 409,600
    float*    bias = (float*)   (ws + 168181760ull);        // NP*4        = 2,560
    float*    zpad = (float*)   (ws + 168184320ull);        // 64 B zeros
    float*    Ach  = (float*)   (ws + 168184576ull);        // 64*32*300*4 = 2,457,600
    float*    Bch  = (float*)   (ws + 170642176ull);        // 2,457,600
    float*    Cin  = (float*)   (ws + 173099776ull);        // 2,457,600

    pack_w<<<(NP * KP + 255) / 256, 256, 0, stream>>>(Wz, Wo, Wc);
    pack_bias<<<1, NP, 0, stream>>>(bz, bo, bias, zpad);

    gemm_zo<<<(M_SZ / 128) * (NP / 128), 256, 0, stream>>>(xin, Wc, bias, zpad, C16);

    scan_p1<<<B_SZ * NCHUNK, 320, 0, stream>>>(gate, C16, Ach, Bch);
    scan_p2<<<(B_SZ * D_SZ + 255) / 256, 256, 0, stream>>>(Ach, Bch, Cin);
    scan_p3<<<B_SZ * NCHUNK, 320, 0, stream>>>(gate, C16, Cin, out);
}

// Round 13
// 311.220 us; speedup vs baseline: 1.0105x; 1.0105x over previous
//
#include <hip/hip_runtime.h>
#include <hip/hip_bf16.h>

typedef _Float16 f16x8 __attribute__((ext_vector_type(8)));
typedef _Float16 f16x4 __attribute__((ext_vector_type(4)));
typedef float f32x4 __attribute__((ext_vector_type(4)));

#define B_SZ 64
#define T_SZ 2048
#define D_SZ 300
#define M_SZ (B_SZ * T_SZ)      // 131072
#define KP 320                   // padded K
#define NP 640                   // padded combined N (z: 0..299, o: 320..619)
#define NCHUNK 32
#define CLEN 64                  // T / NCHUNK
#define SSTR 304                 // scan summary stride (300 padded to x4)

__device__ __forceinline__ void gld_lds16(const void* g, void* l) {
    __builtin_amdgcn_global_load_lds(
        (const __attribute__((address_space(1))) unsigned int*)g,
        (__attribute__((address_space(3))) unsigned int*)l,
        16, 0, 0);
}

__device__ __forceinline__ float fast_tanh(float x) {
    float e = __expf(2.0f * x);
    return 1.0f - 2.0f * __builtin_amdgcn_rcpf(e + 1.0f);
}

// ---- pack X fp32 [M,300] -> fp16 [M,320], vectorized, pad fused ----
__global__ void pack_x(const float* __restrict__ in, _Float16* __restrict__ out) {
    unsigned int i = blockIdx.x * 256u + threadIdx.x;   // grid covers M*80 exactly
    unsigned int row = i / 80;
    unsigned int kq = i - row * 80;
    if (kq < 75) {
        f32x4 v = *(const f32x4*)(in + (size_t)row * D_SZ + kq * 4);
        f16x4 h;
#pragma unroll
        for (int r = 0; r < 4; ++r) h[r] = (_Float16)v[r];
        *(f16x4*)(out + (size_t)row * KP + kq * 4) = h;
    } else {
        f16x4 z = {};
        *(f16x4*)(out + (size_t)row * KP + 300 + (kq - 75) * 4) = z;
    }
}

// ---- pack Wz/Wo fp32 [300,300] -> combined fp16 [640,320], zero-padded ----
__global__ void pack_w(const float* __restrict__ Wz, const float* __restrict__ Wo,
                       _Float16* __restrict__ W) {
    unsigned int i = blockIdx.x * 256u + threadIdx.x;
    if (i >= NP * KP) return;
    unsigned int n = i / KP;
    unsigned int k = i - n * KP;
    float v = 0.0f;
    if (k < D_SZ) {
        if (n < D_SZ) v = Wz[n * D_SZ + k];
        else if (n >= 320 && n < 320 + D_SZ) v = Wo[(n - 320) * D_SZ + k];
    }
    W[i] = (_Float16)v;
}

__global__ void pack_bias(const float* __restrict__ bz, const float* __restrict__ bo,
                          float* __restrict__ bias) {
    int n = threadIdx.x;
    float v = 0.0f;
    if (n < D_SZ) v = bz[n];
    else if (n >= 320 && n < 320 + D_SZ) v = bo[n - 320];
    bias[n] = v;
}

// ---- GEMM: C16[m][n] = tanh( sum_k X[m][k]*W[n][k] + bias[n] ), fp16 out ----
// EXACT R9 (measured 104-106 us): 256x128 tile, BK=32, 8 waves (4x2), gld_lds
// staging (0 conflicts), 2-phase syncthreads loop, swapped MFMA, LDS-shuffle
// epilogue with full 128-B line stores.
__global__ __launch_bounds__(512) void gemm_zo(const _Float16* __restrict__ X,
                                               const _Float16* __restrict__ W,
                                               const float* __restrict__ bias,
                                               _Float16* __restrict__ C) {
    __shared__ _Float16 As[2][256 * 32];   // 32 KB
    __shared__ _Float16 Bs[2][128 * 32];   // 16 KB

    const int tid = threadIdx.x;
    const int lane = tid & 63;
    const int wid = tid >> 6;              // 0..7
    const int wm = wid >> 1, wn = wid & 1; // 4 x 2 wave grid

    // XCD-aware swizzle (2560 blocks, 2560 % 8 == 0 -> bijective)
    int g = blockIdx.x;
    int s = (g & 7) * (2560 / 8) + (g >> 3);
    int bm = s / 5;          // 512 M-tiles
    int bn = s - bm * 5;     // 5 N-tiles

    f32x4 acc[4][4] = {};

    const int r_in_c = lane >> 2;          // row within 16-row chunk
    const int u_phys = lane & 3;           // 16B unit within 64B row

    auto stage = [&](int buf, int kt) {
#pragma unroll
        for (int j = 0; j < 2; ++j) {
            int c = wid + j * 8;
            int row = c * 16 + r_in_c;
            int ul = u_phys ^ ((row >> 1) & 3);   // inverse-swizzled source unit
            const _Float16* ga = X + ((size_t)(bm * 256 + row) * KP + kt * 32 + ul * 8);
            gld_lds16(ga, &As[buf][c * 512]);
        }
        {
            int c = wid;
            int row = c * 16 + r_in_c;
            int ul = u_phys ^ ((row >> 1) & 3);
            const _Float16* gb = W + ((size_t)(bn * 128 + row) * KP + kt * 32 + ul * 8);
            gld_lds16(gb, &Bs[buf][c * 512]);
        }
    };

    stage(0, 0);
    __syncthreads();

    const int l15 = lane & 15;
    const int kq = lane >> 4;

    int buf = 0;
#pragma unroll 1
    for (int kt = 0; kt < 10; ++kt) {
        if (kt < 9) stage(buf ^ 1, kt + 1);

        f16x8 bf[4];
#pragma unroll
        for (int ns = 0; ns < 4; ++ns) {
            int row = wn * 64 + ns * 16 + l15;
            int u = kq ^ ((row >> 1) & 3);
            bf[ns] = *(const f16x8*)&Bs[buf][row * 32 + u * 8];
        }
#pragma unroll
        for (int ms = 0; ms < 4; ++ms) {
            int row = wm * 64 + ms * 16 + l15;
            int u = kq ^ ((row >> 1) & 3);
            f16x8 af = *(const f16x8*)&As[buf][row * 32 + u * 8];
#pragma unroll
            for (int ns = 0; ns < 4; ++ns)
                acc[ms][ns] = __builtin_amdgcn_mfma_f32_16x16x32_f16(bf[ns], af, acc[ms][ns], 0, 0, 0);
        }

        __syncthreads();
        buf ^= 1;
    }

    // ---- epilogue: LDS-shuffled, fully-coalesced full-line stores ----
    __syncthreads();                       // all K-loop LDS reads done; reuse As
    _Float16* et = &As[0][0] + wid * 1024; // [16 rows][64 cols] f16, wave-private

    const int mrow0 = bm * 256 + wm * 64;
    const int ncol0 = bn * 128 + wn * 64;
    const int row8 = lane >> 3;            // 0..7
    const int u8 = lane & 7;               // logical 16B unit within 128B row

    f32x4 b4[4];
#pragma unroll
    for (int ns = 0; ns < 4; ++ns)
        b4[ns] = *(const f32x4*)&bias[ncol0 + ns * 16 + kq * 4];

#pragma unroll
    for (int ms = 0; ms < 4; ++ms) {
#pragma unroll
        for (int ns = 0; ns < 4; ++ns) {
            f16x4 v;
#pragma unroll
            for (int r = 0; r < 4; ++r)
                v[r] = (_Float16)fast_tanh(acc[ms][ns][r] + b4[ns][r]);
            int up = ((ns << 1) | (kq >> 1)) ^ (l15 & 7);
            *(f16x4*)&et[l15 * 64 + up * 8 + (kq & 1) * 4] = v;
        }
#pragma unroll
        for (int j = 0; j < 2; ++j) {
            int rr = row8 + j * 8;
            f16x8 o = *(const f16x8*)&et[rr * 64 + (u8 ^ (rr & 7)) * 8];
            *(f16x8*)&C[(size_t)(mrow0 + ms * 16 + rr) * NP + ncol0 + u8 * 8] = o;
        }
    }
}

// ---- scan phase 1 (vectorized d-quads): per (b, nc, d-quad) chunk affine ----
// block = (nc, b-group-of-4); 300 active threads = 4 subgroups x 75 quads.
// gate reads f32x4 (75 lanes cover a full 1200B row), z reads f16x4.
__global__ void scan_p1(const float* __restrict__ gate, const _Float16* __restrict__ C,
                        float* __restrict__ Aout, float* __restrict__ Bout) {
    int tid = threadIdx.x;
    if (tid >= 300) return;
    int nc = blockIdx.x >> 4;
    int bg = blockIdx.x & 15;
    int sub = tid / 75;
    int q = tid - sub * 75;
    int b = bg * 4 + sub;
    size_t base = (size_t)b * T_SZ + (size_t)nc * CLEN;
    const float* gp = gate + base * D_SZ + q * 4;
    const _Float16* zp = C + base * NP + q * 4;
    f32x4 A = {1.0f, 1.0f, 1.0f, 1.0f};
    f32x4 Bc = {};
#pragma unroll 4
    for (int t = 0; t < CLEN; ++t) {
        f32x4 g = *(const f32x4*)(gp + (size_t)t * D_SZ);
        f16x4 zh = *(const f16x4*)(zp + (size_t)t * NP);
#pragma unroll
        for (int r = 0; r < 4; ++r) {
            A[r] *= g[r];
            Bc[r] = g[r] * Bc[r] + (1.0f - g[r]) * (float)zh[r];
        }
    }
    int o = (b * NCHUNK + nc) * SSTR + q * 4;
    *(f32x4*)&Aout[o] = A;
    *(f32x4*)&Bout[o] = Bc;
}

// ---- scan phase 2: sequential scan over the 32 chunk summaries, f32x4 ----
__global__ void scan_p2(const float* __restrict__ A, const float* __restrict__ Bc,
                        float* __restrict__ Cin) {
    int idx = blockIdx.x * 256 + threadIdx.x;
    if (idx >= B_SZ * 75) return;
    int b = idx / 75;
    int q = idx - b * 75;
    f32x4 c = {};
    for (int nc = 0; nc < NCHUNK; ++nc) {
        int o = (b * NCHUNK + nc) * SSTR + q * 4;
        *(f32x4*)&Cin[o] = c;
        f32x4 Av = *(const f32x4*)&A[o];
        f32x4 Bv = *(const f32x4*)&Bc[o];
#pragma unroll
        for (int r = 0; r < 4; ++r) c[r] = Av[r] * c[r] + Bv[r];
    }
}

// ---- scan phase 3 (vectorized d-quads): replay chunk, write h = o * c ----
__global__ void scan_p3(const float* __restrict__ gate, const _Float16* __restrict__ C,
                        const float* __restrict__ Cin, float* __restrict__ out) {
    int tid = threadIdx.x;
    if (tid >= 300) return;
    int nc = blockIdx.x >> 4;
    int bg = blockIdx.x & 15;
    int sub = tid / 75;
    int q = tid - sub * 75;
    int b = bg * 4 + sub;
    size_t base = (size_t)b * T_SZ + (size_t)nc * CLEN;
    const float* gp = gate + base * D_SZ + q * 4;
    const _Float16* zp = C + base * NP + q * 4;
    const _Float16* op = zp + 320;
    float* hp = out + base * D_SZ + q * 4;
    f32x4 c = *(const f32x4*)&Cin[(b * NCHUNK + nc) * SSTR + q * 4];
#pragma unroll 4
    for (int t = 0; t < CLEN; ++t) {
        f32x4 g = *(const f32x4*)(gp + (size_t)t * D_SZ);
        f16x4 zh = *(const f16x4*)(zp + (size_t)t * NP);
        f16x4 oh = *(const f16x4*)(op + (size_t)t * NP);
        f32x4 h;
#pragma unroll
        for (int r = 0; r < 4; ++r) {
            c[r] = g[r] * c[r] + (1.0f - g[r]) * (float)zh[r];
            h[r] = (float)oh[r] * c[r];
        }
        *(f32x4*)(hp + (size_t)t * D_SZ) = h;
    }
}

extern "C" void kernel_launch(void* const* d_in, const int* in_sizes, int n_in,
                              void* d_out, int out_size, void* d_ws, size_t ws_size,
                              hipStream_t stream) {
    const float* gate = (const float*)d_in[0];
    const float* xin  = (const float*)d_in[1];
    const float* Wz   = (const float*)d_in[2];
    const float* bz   = (const float*)d_in[3];
    const float* Wo   = (const float*)d_in[4];
    const float* bo   = (const float*)d_in[5];
    float* out = (float*)d_out;

    char* ws = (char*)d_ws;
    // workspace layout: Xf16 region is reused by scan summaries after the GEMM.
    _Float16* Xf16 = (_Float16*)(ws);                       // M*KP*2      = 83,886,080
    _Float16* C16  = (_Float16*)(ws + 83886080ull);         // M*NP*2      = 167,772,160
    _Float16* Wc   = (_Float16*)(ws + 251658240ull);        // NP*KP*2     = 409,600
    float*    bias = (float*)   (ws + 252067840ull);        // NP*4        = 2,560
    float*    Ach  = (float*)   (ws);                       // 64*32*304*4 = 2,490,368 (reuses Xf16)
    float*    Bch  = (float*)   (ws + 2490368ull);          // 2,490,368
    float*    Cin  = (float*)   (ws + 4980736ull);          // 2,490,368

    pack_x<<<(M_SZ * 80) / 256, 256, 0, stream>>>(xin, Xf16);
    pack_w<<<(NP * KP + 255) / 256, 256, 0, stream>>>(Wz, Wo, Wc);
    pack_bias<<<1, NP, 0, stream>>>(bz, bo, bias);

    gemm_zo<<<(M_SZ / 256) * (NP / 128), 512, 0, stream>>>(Xf16, Wc, bias, C16);

    scan_p1<<<NCHUNK * 16, 320, 0, stream>>>(gate, C16, Ach, Bch);
    scan_p2<<<(B_SZ * 75 + 255) / 256, 256, 0, stream>>>(Ach, Bch, Cin);
    scan_p3<<<NCHUNK * 16, 320, 0, stream>>>(gate, C16, Cin, out);
}

// Round 14
// 301.438 us; speedup vs baseline: 1.0432x; 1.0325x over previous
//
#include <hip/hip_runtime.h>
#include <hip/hip_bf16.h>

typedef _Float16 f16x8 __attribute__((ext_vector_type(8)));
typedef _Float16 f16x4 __attribute__((ext_vector_type(4)));
typedef float f32x4 __attribute__((ext_vector_type(4)));

#define B_SZ 64
#define T_SZ 2048
#define D_SZ 300
#define M_SZ (B_SZ * T_SZ)      // 131072
#define KP 320                   // padded K
#define NP 640                   // padded combined N (z: 0..299, o: 320..619)
#define NCHUNK 32
#define CLEN 64                  // T / NCHUNK

__device__ __forceinline__ void gld_lds16(const void* g, void* l) {
    __builtin_amdgcn_global_load_lds(
        (const __attribute__((address_space(1))) unsigned int*)g,
        (__attribute__((address_space(3))) unsigned int*)l,
        16, 0, 0);
}

__device__ __forceinline__ float fast_tanh(float x) {
    float e = __expf(2.0f * x);
    return 1.0f - 2.0f * __builtin_amdgcn_rcpf(e + 1.0f);
}

// ---- pack X fp32 [M,300] -> fp16 [M,320], vectorized, pad fused ----
__global__ void pack_x(const float* __restrict__ in, _Float16* __restrict__ out) {
    unsigned int i = blockIdx.x * 256u + threadIdx.x;   // grid covers M*80 exactly
    unsigned int row = i / 80;
    unsigned int kq = i - row * 80;
    if (kq < 75) {
        f32x4 v = *(const f32x4*)(in + (size_t)row * D_SZ + kq * 4);
        f16x4 h;
#pragma unroll
        for (int r = 0; r < 4; ++r) h[r] = (_Float16)v[r];
        *(f16x4*)(out + (size_t)row * KP + kq * 4) = h;
    } else {
        f16x4 z = {};
        *(f16x4*)(out + (size_t)row * KP + 300 + (kq - 75) * 4) = z;
    }
}

// ---- pack Wz/Wo fp32 [300,300] -> combined fp16 [640,320], zero-padded ----
__global__ void pack_w(const float* __restrict__ Wz, const float* __restrict__ Wo,
                       _Float16* __restrict__ W) {
    unsigned int i = blockIdx.x * 256u + threadIdx.x;
    if (i >= NP * KP) return;
    unsigned int n = i / KP;
    unsigned int k = i - n * KP;
    float v = 0.0f;
    if (k < D_SZ) {
        if (n < D_SZ) v = Wz[n * D_SZ + k];
        else if (n >= 320 && n < 320 + D_SZ) v = Wo[(n - 320) * D_SZ + k];
    }
    W[i] = (_Float16)v;
}

__global__ void pack_bias(const float* __restrict__ bz, const float* __restrict__ bo,
                          float* __restrict__ bias) {
    int n = threadIdx.x;
    float v = 0.0f;
    if (n < D_SZ) v = bz[n];
    else if (n >= 320 && n < 320 + D_SZ) v = bo[n - 320];
    bias[n] = v;
}

// ---- GEMM: C16[m][n] = tanh( sum_k X[m][k]*W[n][k] + bias[n] ), fp16 out ----
// Best measured (R9, 302 us total): 256x128 tile, BK=32, 8 waves (4x2),
// gld_lds staging (0 conflicts), 2-phase syncthreads loop, swapped MFMA,
// LDS-shuffle epilogue with full 128-B line stores (the one proven lever:
// 122 -> 104 us; scattered f16x4 stores cost ~18 us in line transactions).
__global__ __launch_bounds__(512) void gemm_zo(const _Float16* __restrict__ X,
                                               const _Float16* __restrict__ W,
                                               const float* __restrict__ bias,
                                               _Float16* __restrict__ C) {
    __shared__ _Float16 As[2][256 * 32];   // 32 KB
    __shared__ _Float16 Bs[2][128 * 32];   // 16 KB

    const int tid = threadIdx.x;
    const int lane = tid & 63;
    const int wid = tid >> 6;              // 0..7
    const int wm = wid >> 1, wn = wid & 1; // 4 x 2 wave grid

    // XCD-aware swizzle (2560 blocks, 2560 % 8 == 0 -> bijective)
    int g = blockIdx.x;
    int s = (g & 7) * (2560 / 8) + (g >> 3);
    int bm = s / 5;          // 512 M-tiles
    int bn = s - bm * 5;     // 5 N-tiles

    f32x4 acc[4][4] = {};

    const int r_in_c = lane >> 2;          // row within 16-row chunk
    const int u_phys = lane & 3;           // 16B unit within 64B row

    auto stage = [&](int buf, int kt) {
#pragma unroll
        for (int j = 0; j < 2; ++j) {
            int c = wid + j * 8;
            int row = c * 16 + r_in_c;
            int ul = u_phys ^ ((row >> 1) & 3);   // inverse-swizzled source unit
            const _Float16* ga = X + ((size_t)(bm * 256 + row) * KP + kt * 32 + ul * 8);
            gld_lds16(ga, &As[buf][c * 512]);
        }
        {
            int c = wid;
            int row = c * 16 + r_in_c;
            int ul = u_phys ^ ((row >> 1) & 3);
            const _Float16* gb = W + ((size_t)(bn * 128 + row) * KP + kt * 32 + ul * 8);
            gld_lds16(gb, &Bs[buf][c * 512]);
        }
    };

    stage(0, 0);
    __syncthreads();

    const int l15 = lane & 15;
    const int kq = lane >> 4;

    int buf = 0;
#pragma unroll 1
    for (int kt = 0; kt < 10; ++kt) {
        if (kt < 9) stage(buf ^ 1, kt + 1);

        f16x8 bf[4];
#pragma unroll
        for (int ns = 0; ns < 4; ++ns) {
            int row = wn * 64 + ns * 16 + l15;
            int u = kq ^ ((row >> 1) & 3);
            bf[ns] = *(const f16x8*)&Bs[buf][row * 32 + u * 8];
        }
#pragma unroll
        for (int ms = 0; ms < 4; ++ms) {
            int row = wm * 64 + ms * 16 + l15;
            int u = kq ^ ((row >> 1) & 3);
            f16x8 af = *(const f16x8*)&As[buf][row * 32 + u * 8];
#pragma unroll
            for (int ns = 0; ns < 4; ++ns)
                acc[ms][ns] = __builtin_amdgcn_mfma_f32_16x16x32_f16(bf[ns], af, acc[ms][ns], 0, 0, 0);
        }

        __syncthreads();
        buf ^= 1;
    }

    // ---- epilogue: LDS-shuffled, fully-coalesced full-line stores ----
    // swapped layout: value (ms,ns,r) sits at m = mrow0+ms*16+l15,
    //                                     n = ncol0+ns*16+kq*4+r
    __syncthreads();                       // all K-loop LDS reads done; reuse As
    _Float16* et = &As[0][0] + wid * 1024; // [16 rows][64 cols] f16, wave-private

    const int mrow0 = bm * 256 + wm * 64;
    const int ncol0 = bn * 128 + wn * 64;
    const int row8 = lane >> 3;            // 0..7
    const int u8 = lane & 7;               // logical 16B unit within 128B row

    f32x4 b4[4];
#pragma unroll
    for (int ns = 0; ns < 4; ++ns)
        b4[ns] = *(const f32x4*)&bias[ncol0 + ns * 16 + kq * 4];

#pragma unroll
    for (int ms = 0; ms < 4; ++ms) {
#pragma unroll
        for (int ns = 0; ns < 4; ++ns) {
            f16x4 v;
#pragma unroll
            for (int r = 0; r < 4; ++r)
                v[r] = (_Float16)fast_tanh(acc[ms][ns][r] + b4[ns][r]);
            // XOR-swizzled write: logical unit ns*2+(kq>>1), half kq&1
            int up = ((ns << 1) | (kq >> 1)) ^ (l15 & 7);
            *(f16x4*)&et[l15 * 64 + up * 8 + (kq & 1) * 4] = v;
        }
        // read back row-contiguous (unswizzle), store full 128-B lines
#pragma unroll
        for (int j = 0; j < 2; ++j) {
            int rr = row8 + j * 8;
            f16x8 o = *(const f16x8*)&et[rr * 64 + (u8 ^ (rr & 7)) * 8];
            *(f16x8*)&C[(size_t)(mrow0 + ms * 16 + rr) * NP + ncol0 + u8 * 8] = o;
        }
    }
}

// ---- scan phase 1: per (b, chunk, d) compute affine (A = prod g, Bc) ----
__global__ void scan_p1(const float* __restrict__ gate, const _Float16* __restrict__ C,
                        float* __restrict__ Aout, float* __restrict__ Bout) {
    int b = blockIdx.x >> 5;
    int nc = blockIdx.x & 31;
    int d = threadIdx.x;
    if (d >= D_SZ) return;
    size_t base = (size_t)b * T_SZ + (size_t)nc * CLEN;
    const float* gp = gate + base * D_SZ + d;
    const _Float16* zp = C + base * NP + d;
    float A = 1.0f, Bc = 0.0f;
    for (int t = 0; t < CLEN; ++t) {
        float gv = gp[(size_t)t * D_SZ];
        float zv = (float)zp[(size_t)t * NP];
        A *= gv;
        Bc = gv * Bc + (1.0f - gv) * zv;
    }
    int o = (b * NCHUNK + nc) * D_SZ + d;
    Aout[o] = A;
    Bout[o] = Bc;
}

// ---- scan phase 2: sequential scan over the 32 chunk summaries ----
__global__ void scan_p2(const float* __restrict__ A, const float* __restrict__ Bc,
                        float* __restrict__ Cin) {
    int idx = blockIdx.x * 256 + threadIdx.x;
    if (idx >= B_SZ * D_SZ) return;
    int b = idx / D_SZ;
    int d = idx - b * D_SZ;
    float c = 0.0f;
    for (int nc = 0; nc < NCHUNK; ++nc) {
        int o = (b * NCHUNK + nc) * D_SZ + d;
        Cin[o] = c;
        c = A[o] * c + Bc[o];
    }
}

// ---- scan phase 3: replay chunk with correct c_in, write h = o * c ----
__global__ void scan_p3(const float* __restrict__ gate, const _Float16* __restrict__ C,
                        const float* __restrict__ Cin, float* __restrict__ out) {
    int b = blockIdx.x >> 5;
    int nc = blockIdx.x & 31;
    int d = threadIdx.x;
    if (d >= D_SZ) return;
    size_t base = (size_t)b * T_SZ + (size_t)nc * CLEN;
    const float* gp = gate + base * D_SZ + d;
    const _Float16* zp = C + base * NP + d;
    const _Float16* op = zp + 320;
    float* hp = out + base * D_SZ + d;
    float c = Cin[(b * NCHUNK + nc) * D_SZ + d];
    for (int t = 0; t < CLEN; ++t) {
        float gv = gp[(size_t)t * D_SZ];
        float zv = (float)zp[(size_t)t * NP];
        float ov = (float)op[(size_t)t * NP];
        c = gv * c + (1.0f - gv) * zv;
        hp[(size_t)t * D_SZ] = ov * c;
    }
}

extern "C" void kernel_launch(void* const* d_in, const int* in_sizes, int n_in,
                              void* d_out, int out_size, void* d_ws, size_t ws_size,
                              hipStream_t stream) {
    const float* gate = (const float*)d_in[0];
    const float* xin  = (const float*)d_in[1];
    const float* Wz   = (const float*)d_in[2];
    const float* bz   = (const float*)d_in[3];
    const float* Wo   = (const float*)d_in[4];
    const float* bo   = (const float*)d_in[5];
    float* out = (float*)d_out;

    char* ws = (char*)d_ws;
    // workspace layout: Xf16 region is reused by scan summaries after the GEMM.
    _Float16* Xf16 = (_Float16*)(ws);                       // M*KP*2      = 83,886,080
    _Float16* C16  = (_Float16*)(ws + 83886080ull);         // M*NP*2      = 167,772,160
    _Float16* Wc   = (_Float16*)(ws + 251658240ull);        // NP*KP*2     = 409,600
    float*    bias = (float*)   (ws + 252067840ull);        // NP*4        = 2,560
    float*    Ach  = (float*)   (ws);                       // 64*32*300*4 = 2,457,600 (reuses Xf16)
    float*    Bch  = (float*)   (ws + 2457600ull);          // 2,457,600
    float*    Cin  = (float*)   (ws + 4915200ull);          // 2,457,600

    pack_x<<<(M_SZ * 80) / 256, 256, 0, stream>>>(xin, Xf16);
    pack_w<<<(NP * KP + 255) / 256, 256, 0, stream>>>(Wz, Wo, Wc);
    pack_bias<<<1, NP, 0, stream>>>(bz, bo, bias);

    gemm_zo<<<(M_SZ / 256) * (NP / 128), 512, 0, stream>>>(Xf16, Wc, bias, C16);

    scan_p1<<<B_SZ * NCHUNK, 320, 0, stream>>>(gate, C16, Ach, Bch);
    scan_p2<<<(B_SZ * D_SZ + 255) / 256, 256, 0, stream>>>(Ach, Bch, Cin);
    scan_p3<<<B_SZ * NCHUNK, 320, 0, stream>>>(gate, C16, Cin, out);
}